// Round 9
// baseline (174.348 us; speedup 1.0000x reference)
//
#include <hip/hip_runtime.h>

// Varifold loss, round 9: 32x32x16 f16 MFMA; SINGLE accumulator pair
// (32 AGPRs, not 64 -> 6-7 waves/EU instead of 4) + B-frag depth-1 register
// prefetch; SPLITS=13 -> 4056 blocks ~= 2 x 2048 (two full residency
// rounds, kills tail quantization). Latency hiding via occupancy (TLP),
// not deep per-wave pipelining.
//
// t_ij = cq_i + cq_j + TG*<C_i,C_j>;  d_ij = <m_i,m_j>;  term = exp2(t)*d^2.
// A-op K=16: [TGh(3),TGl(3),TGh(3),TGl(3),cqh,cql,1,1]
// B-op K=16: [Ch(3),Ch(3),Cl(3),Cl(3),1,1,cqh,cql]
// d:  A=[mh,ml,mh,ml,0^4], B=[mh,mh,ml,ml,0^4]   (exact hi/lo split)

#define NVERT 5023
#define NFACE 9976
#define BATCH 4
#define HALFP 9984             // per-mesh faces padded to x128
#define NTP   (2 * HALFP)      // 19968 faces per batch
#define NTOT  (BATCH * NTP)    // 79872
#define NCH   624              // j-chunks of 32 per batch
#define NPAN  156              // i-panels of 128
#define SPLITS 13

constexpr float GAMMA = 1.0f / (0.03f * 0.03f);
constexpr float LOG2E = 1.4426950408889634f;
constexpr float EPSV  = 1e-12f;

typedef _Float16 half8_t  __attribute__((ext_vector_type(8)));
typedef float    f32x16   __attribute__((ext_vector_type(16)));

__global__ __launch_bounds__(256)
void face_quant_kernel(const float* __restrict__ pred,
                       const float* __restrict__ targ,
                       const int*   __restrict__ faces,
                       _Float16*    __restrict__ fd,
                       float*       __restrict__ out) {
    int idx = blockIdx.x * 256 + threadIdx.x;
    if (idx == 0) out[0] = 0.0f;
    if (idx >= NTOT) return;

    int b     = idx / NTP;
    int s     = idx - b * NTP;
    int which = (s >= HALFP) ? 1 : 0;
    int f     = s - which * HALFP;

    _Float16* arec = fd + (size_t)idx * 32;
    _Float16* brec = fd + (size_t)NTOT * 32 + (size_t)idx * 32;

    if (f >= NFACE) {
        half8_t z = {};
        *(half8_t*)(arec + 0) = z; *(half8_t*)(arec + 8)  = z;
        *(half8_t*)(arec + 16) = z; *(half8_t*)(arec + 24) = z;
        *(half8_t*)(brec + 0) = z; *(half8_t*)(brec + 8)  = z;
        *(half8_t*)(brec + 16) = z; *(half8_t*)(brec + 24) = z;
        return;
    }

    const float* V = (which ? targ : pred) + (size_t)b * NVERT * 3;
    int i0 = faces[f * 3 + 0];
    int i1 = faces[f * 3 + 1];
    int i2 = faces[f * 3 + 2];

    float v0x = V[i0*3+0], v0y = V[i0*3+1], v0z = V[i0*3+2];
    float v1x = V[i1*3+0], v1y = V[i1*3+1], v1z = V[i1*3+2];
    float v2x = V[i2*3+0], v2y = V[i2*3+1], v2z = V[i2*3+2];

    const float third = 1.0f / 3.0f;
    float cx = (v0x + v1x + v2x) * third;
    float cy = (v0y + v1y + v2y) * third;
    float cz = (v0z + v1z + v2z) * third;

    float e1x = v1x - v0x, e1y = v1y - v0y, e1z = v1z - v0z;
    float e2x = v2x - v0x, e2y = v2y - v0y, e2z = v2z - v0z;

    float nx = 0.5f * (e1y * e2z - e1z * e2y);
    float ny = 0.5f * (e1z * e2x - e1x * e2z);
    float nz = 0.5f * (e1x * e2y - e1y * e2x);

    float L   = sqrtf(nx*nx + ny*ny + nz*nz);
    float inv = 1.0f / fmaxf(L, EPSV);
    float sc  = inv * sqrtf(L);            // m = Nn*sqrt(L)
    float mx = nx * sc, my = ny * sc, mz = nz * sc;

    const float TG = 2.0f * GAMMA * LOG2E;
    float tgx = TG * cx, tgy = TG * cy, tgz = TG * cz;
    float cq  = -GAMMA * LOG2E * (cx*cx + cy*cy + cz*cz);

    _Float16 TGxh = (_Float16)tgx; _Float16 TGxl = (_Float16)(tgx - (float)TGxh);
    _Float16 TGyh = (_Float16)tgy; _Float16 TGyl = (_Float16)(tgy - (float)TGyh);
    _Float16 TGzh = (_Float16)tgz; _Float16 TGzl = (_Float16)(tgz - (float)TGzh);
    _Float16 Cxh  = (_Float16)cx;  _Float16 Cxl  = (_Float16)(cx  - (float)Cxh);
    _Float16 Cyh  = (_Float16)cy;  _Float16 Cyl  = (_Float16)(cy  - (float)Cyh);
    _Float16 Czh  = (_Float16)cz;  _Float16 Czl  = (_Float16)(cz  - (float)Czh);
    _Float16 cqh  = (_Float16)cq;  _Float16 cql  = (_Float16)(cq  - (float)cqh);
    _Float16 mxh  = (_Float16)mx;  _Float16 mxl  = (_Float16)(mx  - (float)mxh);
    _Float16 myh  = (_Float16)my;  _Float16 myl  = (_Float16)(my  - (float)myh);
    _Float16 mzh  = (_Float16)mz;  _Float16 mzl  = (_Float16)(mz  - (float)mzh);
    _Float16 one  = (_Float16)1.0f;
    _Float16 zz   = (_Float16)0.0f;

    half8_t ta0 = {TGxh, TGyh, TGzh, TGxl, TGyl, TGzl, TGxh, TGyh};
    half8_t ta1 = {TGzh, TGxl, TGyl, TGzl, cqh,  cql,  one,  one };
    half8_t da0 = {mxh,  myh,  mzh,  mxl,  myl,  mzl,  mxh,  myh };
    half8_t da1 = {mzh,  mxl,  myl,  mzl,  zz,   zz,   zz,   zz  };
    half8_t tb0 = {Cxh,  Cyh,  Czh,  Cxh,  Cyh,  Czh,  Cxl,  Cyl };
    half8_t tb1 = {Czl,  Cxl,  Cyl,  Czl,  one,  one,  cqh,  cql };
    half8_t db0 = {mxh,  myh,  mzh,  mxh,  myh,  mzh,  mxl,  myl };
    half8_t db1 = {mzl,  mxl,  myl,  mzl,  zz,   zz,   zz,   zz  };

    *(half8_t*)(arec + 0)  = ta0;  *(half8_t*)(arec + 8)  = ta1;
    *(half8_t*)(arec + 16) = da0;  *(half8_t*)(arec + 24) = da1;
    *(half8_t*)(brec + 0)  = tb0;  *(half8_t*)(brec + 8)  = tb1;
    *(half8_t*)(brec + 16) = db0;  *(half8_t*)(brec + 24) = db1;
}

__device__ __forceinline__ half8_t ld8(const _Float16* p) {
    return *(const half8_t*)p;
}

__global__ __launch_bounds__(256, 6)
void pair_sum_kernel(const _Float16* __restrict__ fd,
                     float*          __restrict__ out) {
    const int b       = blockIdx.z;
    const int pairIdx = blockIdx.x / SPLITS;     // 0..77
    const int s       = blockIdx.x % SPLITS;

    const _Float16* Arec = fd;
    const _Float16* Brec = fd + (size_t)NTOT * 32;

    const int lane = threadIdx.x & 63;
    const int w    = threadIdx.x >> 6;
    const int col  = lane & 31;
    const int koff = (lane >> 5) * 8;

    const size_t bface = (size_t)b * NTP;
    const size_t JSTEP = (size_t)SPLITS * 32 * 32;   // SPLITS chunks x 32 faces x 32 halfs

    float acc = 0.0f;

    #pragma unroll 1
    for (int h = 0; h < 2; ++h) {
        const int   P  = h ? (NPAN - 1 - pairIdx) : pairIdx;
        const int   c0 = 4 * P;
        const float si = (P < NPAN / 2) ? 1.0f : -1.0f;
        const int   iters = (NCH - c0 - s + SPLITS - 1) / SPLITS;
        if (iters <= 0) continue;

        // A-frags: i-face = P*128 + w*32 + col
        const _Float16* ap = Arec + (bface + (size_t)(P * 128 + w * 32 + col)) * 32 + koff;
        half8_t aT = ld8(ap);
        half8_t aD = ld8(ap + 16);

        // B pointer for first chunk jc = c0 + s
        const _Float16* pB = Brec + (bface + (size_t)((c0 + s) * 32 + col)) * 32 + koff;
        half8_t bT = ld8(pB);
        half8_t bD = ld8(pB + 16);

        #pragma unroll 1
        for (int k = 0; k < iters; ++k) {
            // depth-1 branchless register prefetch of next chunk (clamped)
            const _Float16* pN = (k + 1 < iters) ? (pB + JSTEP) : pB;
            half8_t nT = ld8(pN);
            half8_t nD = ld8(pN + 16);
            pB = pN;

            f32x16 z = {};
            f32x16 T = __builtin_amdgcn_mfma_f32_32x32x16_f16(aT, bT, z, 0, 0, 0);
            f32x16 D = __builtin_amdgcn_mfma_f32_32x32x16_f16(aD, bD, z, 0, 0, 0);

            float ts0 = 0.f, ts1 = 0.f;
            #pragma unroll
            for (int r = 0; r < 16; r += 2) {
                float e0 = __builtin_amdgcn_exp2f(T[r]);
                float d0 = D[r];
                ts0 = fmaf(e0, d0 * d0, ts0);
                float e1 = __builtin_amdgcn_exp2f(T[r + 1]);
                float d1 = D[r + 1];
                ts1 = fmaf(e1, d1 * d1, ts1);
            }

            const int   jc  = c0 + s + SPLITS * k;
            const float sj  = (jc < NCH / 2) ? si : -si;
            const float wgt = (k == 0 && s < 4) ? 1.0f : 2.0f;
            acc = fmaf(sj * wgt * (1.0f / BATCH), ts0 + ts1, acc);

            bT = nT; bD = nD;
        }
    }

    #pragma unroll
    for (int off = 32; off > 0; off >>= 1)
        acc += __shfl_down(acc, off, 64);

    __shared__ float wsum[4];
    if (lane == 0) wsum[w] = acc;
    __syncthreads();
    if (threadIdx.x == 0)
        atomicAdd(out, wsum[0] + wsum[1] + wsum[2] + wsum[3]);
}

extern "C" void kernel_launch(void* const* d_in, const int* in_sizes, int n_in,
                              void* d_out, int out_size, void* d_ws, size_t ws_size,
                              hipStream_t stream) {
    const float* pred  = (const float*)d_in[0];
    const float* targ  = (const float*)d_in[1];
    const int*   faces = (const int*)d_in[2];
    float*       out   = (float*)d_out;
    _Float16*    fd    = (_Float16*)d_ws;   // 2 arrays x 79872 faces x 64 B = 10.2 MB

    face_quant_kernel<<<(NTOT + 255) / 256, 256, 0, stream>>>(
        pred, targ, faces, fd, out);

    dim3 grid((NPAN / 2) * SPLITS, 1, BATCH);   // 1014 x 1 x 4 = 4056 blocks
    pair_sum_kernel<<<grid, 256, 0, stream>>>(fd, out);
}

// Round 10
// 171.241 us; speedup vs baseline: 1.0181x; 1.0181x over previous
//
#include <hip/hip_runtime.h>

// Varifold loss, round 10: 32x32x16 f16 MFMA; depth-2 MFMA software
// pipeline (R8) + SPLITS=13 two-round grid (R9) + packed-f32 epilogue
// (v_pk_mul/v_pk_fma halve epilogue VALU + temps) + launch_bounds(256,5)
// to hold 5 waves/EU with the 64-reg accumulator pipeline.
//
// t_ij = cq_i + cq_j + TG*<C_i,C_j>;  d_ij = <m_i,m_j>;  term = exp2(t)*d^2.
// A-op K=16: [TGh(3),TGl(3),TGh(3),TGl(3),cqh,cql,1,1]
// B-op K=16: [Ch(3),Ch(3),Cl(3),Cl(3),1,1,cqh,cql]
// d:  A=[mh,ml,mh,ml,0^4], B=[mh,mh,ml,ml,0^4]   (exact hi/lo split)

#define NVERT 5023
#define NFACE 9976
#define BATCH 4
#define HALFP 9984             // per-mesh faces padded to x128
#define NTP   (2 * HALFP)      // 19968 faces per batch
#define NTOT  (BATCH * NTP)    // 79872
#define NCH   624              // j-chunks of 32 per batch
#define NPAN  156              // i-panels of 128
#define SPLITS 13

constexpr float GAMMA = 1.0f / (0.03f * 0.03f);
constexpr float LOG2E = 1.4426950408889634f;
constexpr float EPSV  = 1e-12f;

typedef _Float16 half8_t  __attribute__((ext_vector_type(8)));
typedef float    f32x16   __attribute__((ext_vector_type(16)));
typedef float    f32x2    __attribute__((ext_vector_type(2)));

__global__ __launch_bounds__(256)
void face_quant_kernel(const float* __restrict__ pred,
                       const float* __restrict__ targ,
                       const int*   __restrict__ faces,
                       _Float16*    __restrict__ fd,
                       float*       __restrict__ out) {
    int idx = blockIdx.x * 256 + threadIdx.x;
    if (idx == 0) out[0] = 0.0f;
    if (idx >= NTOT) return;

    int b     = idx / NTP;
    int s     = idx - b * NTP;
    int which = (s >= HALFP) ? 1 : 0;
    int f     = s - which * HALFP;

    _Float16* arec = fd + (size_t)idx * 32;
    _Float16* brec = fd + (size_t)NTOT * 32 + (size_t)idx * 32;

    if (f >= NFACE) {
        half8_t z = {};
        *(half8_t*)(arec + 0) = z; *(half8_t*)(arec + 8)  = z;
        *(half8_t*)(arec + 16) = z; *(half8_t*)(arec + 24) = z;
        *(half8_t*)(brec + 0) = z; *(half8_t*)(brec + 8)  = z;
        *(half8_t*)(brec + 16) = z; *(half8_t*)(brec + 24) = z;
        return;
    }

    const float* V = (which ? targ : pred) + (size_t)b * NVERT * 3;
    int i0 = faces[f * 3 + 0];
    int i1 = faces[f * 3 + 1];
    int i2 = faces[f * 3 + 2];

    float v0x = V[i0*3+0], v0y = V[i0*3+1], v0z = V[i0*3+2];
    float v1x = V[i1*3+0], v1y = V[i1*3+1], v1z = V[i1*3+2];
    float v2x = V[i2*3+0], v2y = V[i2*3+1], v2z = V[i2*3+2];

    const float third = 1.0f / 3.0f;
    float cx = (v0x + v1x + v2x) * third;
    float cy = (v0y + v1y + v2y) * third;
    float cz = (v0z + v1z + v2z) * third;

    float e1x = v1x - v0x, e1y = v1y - v0y, e1z = v1z - v0z;
    float e2x = v2x - v0x, e2y = v2y - v0y, e2z = v2z - v0z;

    float nx = 0.5f * (e1y * e2z - e1z * e2y);
    float ny = 0.5f * (e1z * e2x - e1x * e2z);
    float nz = 0.5f * (e1x * e2y - e1y * e2x);

    float L   = sqrtf(nx*nx + ny*ny + nz*nz);
    float inv = 1.0f / fmaxf(L, EPSV);
    float sc  = inv * sqrtf(L);            // m = Nn*sqrt(L)
    float mx = nx * sc, my = ny * sc, mz = nz * sc;

    const float TG = 2.0f * GAMMA * LOG2E;
    float tgx = TG * cx, tgy = TG * cy, tgz = TG * cz;
    float cq  = -GAMMA * LOG2E * (cx*cx + cy*cy + cz*cz);

    _Float16 TGxh = (_Float16)tgx; _Float16 TGxl = (_Float16)(tgx - (float)TGxh);
    _Float16 TGyh = (_Float16)tgy; _Float16 TGyl = (_Float16)(tgy - (float)TGyh);
    _Float16 TGzh = (_Float16)tgz; _Float16 TGzl = (_Float16)(tgz - (float)TGzh);
    _Float16 Cxh  = (_Float16)cx;  _Float16 Cxl  = (_Float16)(cx  - (float)Cxh);
    _Float16 Cyh  = (_Float16)cy;  _Float16 Cyl  = (_Float16)(cy  - (float)Cyh);
    _Float16 Czh  = (_Float16)cz;  _Float16 Czl  = (_Float16)(cz  - (float)Czh);
    _Float16 cqh  = (_Float16)cq;  _Float16 cql  = (_Float16)(cq  - (float)cqh);
    _Float16 mxh  = (_Float16)mx;  _Float16 mxl  = (_Float16)(mx  - (float)mxh);
    _Float16 myh  = (_Float16)my;  _Float16 myl  = (_Float16)(my  - (float)myh);
    _Float16 mzh  = (_Float16)mz;  _Float16 mzl  = (_Float16)(mz  - (float)mzh);
    _Float16 one  = (_Float16)1.0f;
    _Float16 zz   = (_Float16)0.0f;

    half8_t ta0 = {TGxh, TGyh, TGzh, TGxl, TGyl, TGzl, TGxh, TGyh};
    half8_t ta1 = {TGzh, TGxl, TGyl, TGzl, cqh,  cql,  one,  one };
    half8_t da0 = {mxh,  myh,  mzh,  mxl,  myl,  mzl,  mxh,  myh };
    half8_t da1 = {mzh,  mxl,  myl,  mzl,  zz,   zz,   zz,   zz  };
    half8_t tb0 = {Cxh,  Cyh,  Czh,  Cxh,  Cyh,  Czh,  Cxl,  Cyl };
    half8_t tb1 = {Czl,  Cxl,  Cyl,  Czl,  one,  one,  cqh,  cql };
    half8_t db0 = {mxh,  myh,  mzh,  mxh,  myh,  mzh,  mxl,  myl };
    half8_t db1 = {mzl,  mxl,  myl,  mzl,  zz,   zz,   zz,   zz  };

    *(half8_t*)(arec + 0)  = ta0;  *(half8_t*)(arec + 8)  = ta1;
    *(half8_t*)(arec + 16) = da0;  *(half8_t*)(arec + 24) = da1;
    *(half8_t*)(brec + 0)  = tb0;  *(half8_t*)(brec + 8)  = tb1;
    *(half8_t*)(brec + 16) = db0;  *(half8_t*)(brec + 24) = db1;
}

__device__ __forceinline__ half8_t ld8(const _Float16* p) {
    return *(const half8_t*)p;
}

__global__ __launch_bounds__(256, 5)
void pair_sum_kernel(const _Float16* __restrict__ fd,
                     float*          __restrict__ out) {
    const int b       = blockIdx.z;
    const int pairIdx = blockIdx.x / SPLITS;     // 0..77
    const int s       = blockIdx.x % SPLITS;

    const _Float16* Arec = fd;
    const _Float16* Brec = fd + (size_t)NTOT * 32;

    const int lane = threadIdx.x & 63;
    const int w    = threadIdx.x >> 6;
    const int col  = lane & 31;
    const int koff = (lane >> 5) * 8;

    const size_t bface = (size_t)b * NTP;
    const size_t JSTEP = (size_t)SPLITS * 32 * 32;

    float acc = 0.0f;

    #pragma unroll 1
    for (int h = 0; h < 2; ++h) {
        const int   P  = h ? (NPAN - 1 - pairIdx) : pairIdx;
        const int   c0 = 4 * P;
        const float si = (P < NPAN / 2) ? 1.0f : -1.0f;
        const int   iters = (NCH - c0 - s + SPLITS - 1) / SPLITS;
        if (iters <= 0) continue;

        // A-frags: i-face = P*128 + w*32 + col
        const _Float16* ap = Arec + (bface + (size_t)(P * 128 + w * 32 + col)) * 32 + koff;
        half8_t aT = ld8(ap);
        half8_t aD = ld8(ap + 16);

        // pipeline prologue: load B(0), MFMA(0), load B(1)
        const _Float16* pB = Brec + (bface + (size_t)((c0 + s) * 32 + col)) * 32 + koff;
        half8_t bT = ld8(pB);
        half8_t bD = ld8(pB + 16);

        f32x16 z  = {};
        f32x16 Tp = __builtin_amdgcn_mfma_f32_32x32x16_f16(aT, bT, z, 0, 0, 0);
        f32x16 Dp = __builtin_amdgcn_mfma_f32_32x32x16_f16(aD, bD, z, 0, 0, 0);

        pB = (iters > 1) ? (pB + JSTEP) : pB;
        bT = ld8(pB);
        bD = ld8(pB + 16);

        #pragma unroll 1
        for (int k = 0; k < iters; ++k) {
            // issue MFMA for chunk k+1 (result discarded when k+1 == iters)
            f32x16 Tn = __builtin_amdgcn_mfma_f32_32x32x16_f16(aT, bT, z, 0, 0, 0);
            f32x16 Dn = __builtin_amdgcn_mfma_f32_32x32x16_f16(aD, bD, z, 0, 0, 0);

            // prefetch B for chunk k+2 (clamped in-bounds)
            const _Float16* pN = (k + 2 < iters) ? (pB + JSTEP) : pB;
            half8_t nT = ld8(pN);
            half8_t nD = ld8(pN + 16);
            pB = pN;

            // packed epilogue on chunk k's results
            f32x2 ts2 = {0.f, 0.f};
            #pragma unroll
            for (int r = 0; r < 16; r += 2) {
                f32x2 ee = {__builtin_amdgcn_exp2f(Tp[r]),
                            __builtin_amdgcn_exp2f(Tp[r + 1])};
                f32x2 dd = {Dp[r], Dp[r + 1]};
                dd = dd * dd;                   // v_pk_mul_f32
                ts2 = ee * dd + ts2;            // v_pk_fma_f32
            }

            const int   jc  = c0 + s + SPLITS * k;
            const float sj  = (jc < NCH / 2) ? si : -si;
            const float wgt = (k == 0 && s < 4) ? 1.0f : 2.0f;
            acc = fmaf(sj * wgt * (1.0f / BATCH), ts2.x + ts2.y, acc);

            Tp = Tn; Dp = Dn;
            bT = nT; bD = nD;
        }
    }

    #pragma unroll
    for (int off = 32; off > 0; off >>= 1)
        acc += __shfl_down(acc, off, 64);

    __shared__ float wsum[4];
    if (lane == 0) wsum[w] = acc;
    __syncthreads();
    if (threadIdx.x == 0)
        atomicAdd(out, wsum[0] + wsum[1] + wsum[2] + wsum[3]);
}

extern "C" void kernel_launch(void* const* d_in, const int* in_sizes, int n_in,
                              void* d_out, int out_size, void* d_ws, size_t ws_size,
                              hipStream_t stream) {
    const float* pred  = (const float*)d_in[0];
    const float* targ  = (const float*)d_in[1];
    const int*   faces = (const int*)d_in[2];
    float*       out   = (float*)d_out;
    _Float16*    fd    = (_Float16*)d_ws;   // 2 arrays x 79872 faces x 64 B = 10.2 MB

    face_quant_kernel<<<(NTOT + 255) / 256, 256, 0, stream>>>(
        pred, targ, faces, fd, out);

    dim3 grid((NPAN / 2) * SPLITS, 1, BATCH);   // 1014 x 1 x 4 = 4056 blocks
    pair_sum_kernel<<<grid, 256, 0, stream>>>(fd, out);
}

// Round 11
// 168.788 us; speedup vs baseline: 1.0329x; 1.0145x over previous
//
#include <hip/hip_runtime.h>

// Varifold loss, round 11: 32x32x16 f16 MFMA; k-loop unrolled by 2 with
// ping-pong C-register sets (T0/D0, T1/D1) — two independent chunk
// epilogues per trip fill issue slots during trans bursts / MFMA waits,
// no accumulator rotation moves. launch_bounds(256,4).
//
// t_ij = cq_i + cq_j + TG*<C_i,C_j>;  d_ij = <m_i,m_j>;  term = exp2(t)*d^2.
// A-op K=16: [TGh(3),TGl(3),TGh(3),TGl(3),cqh,cql,1,1]
// B-op K=16: [Ch(3),Ch(3),Cl(3),Cl(3),1,1,cqh,cql]
// d:  A=[mh,ml,mh,ml,0^4], B=[mh,mh,ml,ml,0^4]   (exact hi/lo split)

#define NVERT 5023
#define NFACE 9976
#define BATCH 4
#define HALFP 9984             // per-mesh faces padded to x128
#define NTP   (2 * HALFP)      // 19968 faces per batch
#define NTOT  (BATCH * NTP)    // 79872
#define NCH   624              // j-chunks of 32 per batch
#define NPAN  156              // i-panels of 128
#define SPLITS 13

constexpr float GAMMA = 1.0f / (0.03f * 0.03f);
constexpr float LOG2E = 1.4426950408889634f;
constexpr float EPSV  = 1e-12f;

typedef _Float16 half8_t  __attribute__((ext_vector_type(8)));
typedef float    f32x16   __attribute__((ext_vector_type(16)));
typedef float    f32x2    __attribute__((ext_vector_type(2)));

__global__ __launch_bounds__(256)
void face_quant_kernel(const float* __restrict__ pred,
                       const float* __restrict__ targ,
                       const int*   __restrict__ faces,
                       _Float16*    __restrict__ fd,
                       float*       __restrict__ out) {
    int idx = blockIdx.x * 256 + threadIdx.x;
    if (idx == 0) out[0] = 0.0f;
    if (idx >= NTOT) return;

    int b     = idx / NTP;
    int s     = idx - b * NTP;
    int which = (s >= HALFP) ? 1 : 0;
    int f     = s - which * HALFP;

    _Float16* arec = fd + (size_t)idx * 32;
    _Float16* brec = fd + (size_t)NTOT * 32 + (size_t)idx * 32;

    if (f >= NFACE) {
        half8_t z = {};
        *(half8_t*)(arec + 0) = z; *(half8_t*)(arec + 8)  = z;
        *(half8_t*)(arec + 16) = z; *(half8_t*)(arec + 24) = z;
        *(half8_t*)(brec + 0) = z; *(half8_t*)(brec + 8)  = z;
        *(half8_t*)(brec + 16) = z; *(half8_t*)(brec + 24) = z;
        return;
    }

    const float* V = (which ? targ : pred) + (size_t)b * NVERT * 3;
    int i0 = faces[f * 3 + 0];
    int i1 = faces[f * 3 + 1];
    int i2 = faces[f * 3 + 2];

    float v0x = V[i0*3+0], v0y = V[i0*3+1], v0z = V[i0*3+2];
    float v1x = V[i1*3+0], v1y = V[i1*3+1], v1z = V[i1*3+2];
    float v2x = V[i2*3+0], v2y = V[i2*3+1], v2z = V[i2*3+2];

    const float third = 1.0f / 3.0f;
    float cx = (v0x + v1x + v2x) * third;
    float cy = (v0y + v1y + v2y) * third;
    float cz = (v0z + v1z + v2z) * third;

    float e1x = v1x - v0x, e1y = v1y - v0y, e1z = v1z - v0z;
    float e2x = v2x - v0x, e2y = v2y - v0y, e2z = v2z - v0z;

    float nx = 0.5f * (e1y * e2z - e1z * e2y);
    float ny = 0.5f * (e1z * e2x - e1x * e2z);
    float nz = 0.5f * (e1x * e2y - e1y * e2x);

    float L   = sqrtf(nx*nx + ny*ny + nz*nz);
    float inv = 1.0f / fmaxf(L, EPSV);
    float sc  = inv * sqrtf(L);            // m = Nn*sqrt(L)
    float mx = nx * sc, my = ny * sc, mz = nz * sc;

    const float TG = 2.0f * GAMMA * LOG2E;
    float tgx = TG * cx, tgy = TG * cy, tgz = TG * cz;
    float cq  = -GAMMA * LOG2E * (cx*cx + cy*cy + cz*cz);

    _Float16 TGxh = (_Float16)tgx; _Float16 TGxl = (_Float16)(tgx - (float)TGxh);
    _Float16 TGyh = (_Float16)tgy; _Float16 TGyl = (_Float16)(tgy - (float)TGyh);
    _Float16 TGzh = (_Float16)tgz; _Float16 TGzl = (_Float16)(tgz - (float)TGzh);
    _Float16 Cxh  = (_Float16)cx;  _Float16 Cxl  = (_Float16)(cx  - (float)Cxh);
    _Float16 Cyh  = (_Float16)cy;  _Float16 Cyl  = (_Float16)(cy  - (float)Cyh);
    _Float16 Czh  = (_Float16)cz;  _Float16 Czl  = (_Float16)(cz  - (float)Czh);
    _Float16 cqh  = (_Float16)cq;  _Float16 cql  = (_Float16)(cq  - (float)cqh);
    _Float16 mxh  = (_Float16)mx;  _Float16 mxl  = (_Float16)(mx  - (float)mxh);
    _Float16 myh  = (_Float16)my;  _Float16 myl  = (_Float16)(my  - (float)myh);
    _Float16 mzh  = (_Float16)mz;  _Float16 mzl  = (_Float16)(mz  - (float)mzh);
    _Float16 one  = (_Float16)1.0f;
    _Float16 zz   = (_Float16)0.0f;

    half8_t ta0 = {TGxh, TGyh, TGzh, TGxl, TGyl, TGzl, TGxh, TGyh};
    half8_t ta1 = {TGzh, TGxl, TGyl, TGzl, cqh,  cql,  one,  one };
    half8_t da0 = {mxh,  myh,  mzh,  mxl,  myl,  mzl,  mxh,  myh };
    half8_t da1 = {mzh,  mxl,  myl,  mzl,  zz,   zz,   zz,   zz  };
    half8_t tb0 = {Cxh,  Cyh,  Czh,  Cxh,  Cyh,  Czh,  Cxl,  Cyl };
    half8_t tb1 = {Czl,  Cxl,  Cyl,  Czl,  one,  one,  cqh,  cql };
    half8_t db0 = {mxh,  myh,  mzh,  mxh,  myh,  mzh,  mxl,  myl };
    half8_t db1 = {mzl,  mxl,  myl,  mzl,  zz,   zz,   zz,   zz  };

    *(half8_t*)(arec + 0)  = ta0;  *(half8_t*)(arec + 8)  = ta1;
    *(half8_t*)(arec + 16) = da0;  *(half8_t*)(arec + 24) = da1;
    *(half8_t*)(brec + 0)  = tb0;  *(half8_t*)(brec + 8)  = tb1;
    *(half8_t*)(brec + 16) = db0;  *(half8_t*)(brec + 24) = db1;
}

__device__ __forceinline__ half8_t ld8(const _Float16* p) {
    return *(const half8_t*)p;
}

__global__ __launch_bounds__(256, 4)
void pair_sum_kernel(const _Float16* __restrict__ fd,
                     float*          __restrict__ out) {
    const int b       = blockIdx.z;
    const int pairIdx = blockIdx.x / SPLITS;     // 0..77
    const int s       = blockIdx.x % SPLITS;

    const _Float16* Arec = fd;
    const _Float16* Brec = fd + (size_t)NTOT * 32;

    const int lane = threadIdx.x & 63;
    const int w    = threadIdx.x >> 6;
    const int col  = lane & 31;
    const int koff = (lane >> 5) * 8;

    const size_t bface = (size_t)b * NTP;
    const size_t JSTEP = (size_t)SPLITS * 32 * 32;

    float acc = 0.0f;

    #pragma unroll 1
    for (int h = 0; h < 2; ++h) {
        const int   P  = h ? (NPAN - 1 - pairIdx) : pairIdx;
        const int   c0 = 4 * P;
        const float si = (P < NPAN / 2) ? 1.0f : -1.0f;
        const int   iters = (NCH - c0 - s + SPLITS - 1) / SPLITS;
        if (iters <= 0) continue;

        const _Float16* ap = Arec + (bface + (size_t)(P * 128 + w * 32 + col)) * 32 + koff;
        half8_t aT = ld8(ap);
        half8_t aD = ld8(ap + 16);

        // weight/sign per chunk index k:
        //   jc = c0 + s + SPLITS*k; fac = si * (jc<NCH/2?1:-1) * (k==0&&s<4?1:2)
        #define FAC(k_) (si * (((c0 + s + SPLITS * (k_)) < NCH / 2) ? 1.0f : -1.0f) \
                            * (((k_) == 0 && s < 4) ? 1.0f : 2.0f))

        #define EPILOGUE(T_, D_, k_)                                           \
        {                                                                      \
            f32x2 ts2 = {0.f, 0.f};                                            \
            _Pragma("unroll")                                                  \
            for (int r = 0; r < 16; r += 2) {                                  \
                f32x2 ee = {__builtin_amdgcn_exp2f((T_)[r]),                   \
                            __builtin_amdgcn_exp2f((T_)[r + 1])};              \
                f32x2 dd = {(D_)[r], (D_)[r + 1]};                             \
                dd = dd * dd;                                                  \
                ts2 = ee * dd + ts2;                                           \
            }                                                                  \
            acc = fmaf(FAC(k_), ts2.x + ts2.y, acc);                           \
        }

        // prologue: chunk 0 MFMA in flight, chunk 1 B-frags loading
        const _Float16* pB = Brec + (bface + (size_t)((c0 + s) * 32 + col)) * 32 + koff;
        half8_t bT0 = ld8(pB);
        half8_t bD0 = ld8(pB + 16);

        f32x16 z  = {};
        f32x16 T0 = __builtin_amdgcn_mfma_f32_32x32x16_f16(aT, bT0, z, 0, 0, 0);
        f32x16 D0 = __builtin_amdgcn_mfma_f32_32x32x16_f16(aD, bD0, z, 0, 0, 0);

        const _Float16* pB1 = (iters > 1) ? (pB + JSTEP) : pB;
        half8_t bT1 = ld8(pB1);
        half8_t bD1 = ld8(pB1 + 16);
        pB = pB1;

        int k = 0;
        #pragma unroll 1
        for (; k + 2 < iters; k += 2) {
            // issue chunk k+1 MFMAs; load chunk k+2 (exists: k+2 < iters)
            f32x16 T1 = __builtin_amdgcn_mfma_f32_32x32x16_f16(aT, bT1, z, 0, 0, 0);
            f32x16 D1 = __builtin_amdgcn_mfma_f32_32x32x16_f16(aD, bD1, z, 0, 0, 0);
            pB += JSTEP;
            bT0 = ld8(pB);
            bD0 = ld8(pB + 16);

            EPILOGUE(T0, D0, k);

            // issue chunk k+2 MFMAs; load chunk k+3 (clamped)
            T0 = __builtin_amdgcn_mfma_f32_32x32x16_f16(aT, bT0, z, 0, 0, 0);
            D0 = __builtin_amdgcn_mfma_f32_32x32x16_f16(aD, bD0, z, 0, 0, 0);
            const _Float16* pN = (k + 3 < iters) ? (pB + JSTEP) : pB;
            bT1 = ld8(pN);
            bD1 = ld8(pN + 16);
            pB = pN;

            EPILOGUE(T1, D1, k + 1);
        }

        if (iters - k == 2) {
            f32x16 T1 = __builtin_amdgcn_mfma_f32_32x32x16_f16(aT, bT1, z, 0, 0, 0);
            f32x16 D1 = __builtin_amdgcn_mfma_f32_32x32x16_f16(aD, bD1, z, 0, 0, 0);
            EPILOGUE(T0, D0, k);
            EPILOGUE(T1, D1, k + 1);
        } else {
            EPILOGUE(T0, D0, k);
        }
        #undef EPILOGUE
        #undef FAC
    }

    acc *= (1.0f / BATCH);

    #pragma unroll
    for (int off = 32; off > 0; off >>= 1)
        acc += __shfl_down(acc, off, 64);

    __shared__ float wsum[4];
    if (lane == 0) wsum[w] = acc;
    __syncthreads();
    if (threadIdx.x == 0)
        atomicAdd(out, wsum[0] + wsum[1] + wsum[2] + wsum[3]);
}

extern "C" void kernel_launch(void* const* d_in, const int* in_sizes, int n_in,
                              void* d_out, int out_size, void* d_ws, size_t ws_size,
                              hipStream_t stream) {
    const float* pred  = (const float*)d_in[0];
    const float* targ  = (const float*)d_in[1];
    const int*   faces = (const int*)d_in[2];
    float*       out   = (float*)d_out;
    _Float16*    fd    = (_Float16*)d_ws;   // 2 arrays x 79872 faces x 64 B = 10.2 MB

    face_quant_kernel<<<(NTOT + 255) / 256, 256, 0, stream>>>(
        pred, targ, faces, fd, out);

    dim3 grid((NPAN / 2) * SPLITS, 1, BATCH);   // 1014 x 1 x 4 = 4056 blocks
    pair_sum_kernel<<<grid, 256, 0, stream>>>(fd, out);
}

// Round 12
// 157.135 us; speedup vs baseline: 1.1095x; 1.0742x over previous
//
#include <hip/hip_runtime.h>

// Varifold loss, round 12: 32x32x16 f16 MFMA; each wave runs TWO i-tiles
// (64 rows) against each B-chunk -> one B load feeds 4 MFMAs / 2048 pairs,
// halving loads+addr+loop cost per pair and giving two independent
// epilogue streams. Panels of 256 rows, balanced pairing, SPLITS=26.
//
// t_ij = cq_i + cq_j + TG*<C_i,C_j>;  d_ij = <m_i,m_j>;  term = exp2(t)*d^2.
// A-op K=16: [TGh(3),TGl(3),TGh(3),TGl(3),cqh,cql,1,1]
// B-op K=16: [Ch(3),Ch(3),Cl(3),Cl(3),1,1,cqh,cql]
// d:  A=[mh,ml,mh,ml,0^4], B=[mh,mh,ml,ml,0^4]   (exact hi/lo split)

#define NVERT 5023
#define NFACE 9976
#define BATCH 4
#define HALFP 9984             // per-mesh faces padded: 39 panels x 256
#define NTP   (2 * HALFP)      // 19968 faces per batch
#define NTOT  (BATCH * NTP)    // 79872
#define NCH   624              // j-chunks of 32 per batch
#define NPAN  78               // i-panels of 256
#define SPLITS 26

constexpr float GAMMA = 1.0f / (0.03f * 0.03f);
constexpr float LOG2E = 1.4426950408889634f;
constexpr float EPSV  = 1e-12f;

typedef _Float16 half8_t  __attribute__((ext_vector_type(8)));
typedef float    f32x16   __attribute__((ext_vector_type(16)));
typedef float    f32x2    __attribute__((ext_vector_type(2)));

__global__ __launch_bounds__(256)
void face_quant_kernel(const float* __restrict__ pred,
                       const float* __restrict__ targ,
                       const int*   __restrict__ faces,
                       _Float16*    __restrict__ fd,
                       float*       __restrict__ out) {
    int idx = blockIdx.x * 256 + threadIdx.x;
    if (idx == 0) out[0] = 0.0f;
    if (idx >= NTOT) return;

    int b     = idx / NTP;
    int s     = idx - b * NTP;
    int which = (s >= HALFP) ? 1 : 0;
    int f     = s - which * HALFP;

    _Float16* arec = fd + (size_t)idx * 32;
    _Float16* brec = fd + (size_t)NTOT * 32 + (size_t)idx * 32;

    if (f >= NFACE) {
        half8_t z = {};
        *(half8_t*)(arec + 0) = z; *(half8_t*)(arec + 8)  = z;
        *(half8_t*)(arec + 16) = z; *(half8_t*)(arec + 24) = z;
        *(half8_t*)(brec + 0) = z; *(half8_t*)(brec + 8)  = z;
        *(half8_t*)(brec + 16) = z; *(half8_t*)(brec + 24) = z;
        return;
    }

    const float* V = (which ? targ : pred) + (size_t)b * NVERT * 3;
    int i0 = faces[f * 3 + 0];
    int i1 = faces[f * 3 + 1];
    int i2 = faces[f * 3 + 2];

    float v0x = V[i0*3+0], v0y = V[i0*3+1], v0z = V[i0*3+2];
    float v1x = V[i1*3+0], v1y = V[i1*3+1], v1z = V[i1*3+2];
    float v2x = V[i2*3+0], v2y = V[i2*3+1], v2z = V[i2*3+2];

    const float third = 1.0f / 3.0f;
    float cx = (v0x + v1x + v2x) * third;
    float cy = (v0y + v1y + v2y) * third;
    float cz = (v0z + v1z + v2z) * third;

    float e1x = v1x - v0x, e1y = v1y - v0y, e1z = v1z - v0z;
    float e2x = v2x - v0x, e2y = v2y - v0y, e2z = v2z - v0z;

    float nx = 0.5f * (e1y * e2z - e1z * e2y);
    float ny = 0.5f * (e1z * e2x - e1x * e2z);
    float nz = 0.5f * (e1x * e2y - e1y * e2x);

    float L   = sqrtf(nx*nx + ny*ny + nz*nz);
    float inv = 1.0f / fmaxf(L, EPSV);
    float sc  = inv * sqrtf(L);            // m = Nn*sqrt(L)
    float mx = nx * sc, my = ny * sc, mz = nz * sc;

    const float TG = 2.0f * GAMMA * LOG2E;
    float tgx = TG * cx, tgy = TG * cy, tgz = TG * cz;
    float cq  = -GAMMA * LOG2E * (cx*cx + cy*cy + cz*cz);

    _Float16 TGxh = (_Float16)tgx; _Float16 TGxl = (_Float16)(tgx - (float)TGxh);
    _Float16 TGyh = (_Float16)tgy; _Float16 TGyl = (_Float16)(tgy - (float)TGyh);
    _Float16 TGzh = (_Float16)tgz; _Float16 TGzl = (_Float16)(tgz - (float)TGzh);
    _Float16 Cxh  = (_Float16)cx;  _Float16 Cxl  = (_Float16)(cx  - (float)Cxh);
    _Float16 Cyh  = (_Float16)cy;  _Float16 Cyl  = (_Float16)(cy  - (float)Cyh);
    _Float16 Czh  = (_Float16)cz;  _Float16 Czl  = (_Float16)(cz  - (float)Czh);
    _Float16 cqh  = (_Float16)cq;  _Float16 cql  = (_Float16)(cq  - (float)cqh);
    _Float16 mxh  = (_Float16)mx;  _Float16 mxl  = (_Float16)(mx  - (float)mxh);
    _Float16 myh  = (_Float16)my;  _Float16 myl  = (_Float16)(my  - (float)myh);
    _Float16 mzh  = (_Float16)mz;  _Float16 mzl  = (_Float16)(mz  - (float)mzh);
    _Float16 one  = (_Float16)1.0f;
    _Float16 zz   = (_Float16)0.0f;

    half8_t ta0 = {TGxh, TGyh, TGzh, TGxl, TGyl, TGzl, TGxh, TGyh};
    half8_t ta1 = {TGzh, TGxl, TGyl, TGzl, cqh,  cql,  one,  one };
    half8_t da0 = {mxh,  myh,  mzh,  mxl,  myl,  mzl,  mxh,  myh };
    half8_t da1 = {mzh,  mxl,  myl,  mzl,  zz,   zz,   zz,   zz  };
    half8_t tb0 = {Cxh,  Cyh,  Czh,  Cxh,  Cyh,  Czh,  Cxl,  Cyl };
    half8_t tb1 = {Czl,  Cxl,  Cyl,  Czl,  one,  one,  cqh,  cql };
    half8_t db0 = {mxh,  myh,  mzh,  mxh,  myh,  mzh,  mxl,  myl };
    half8_t db1 = {mzl,  mxl,  myl,  mzl,  zz,   zz,   zz,   zz  };

    *(half8_t*)(arec + 0)  = ta0;  *(half8_t*)(arec + 8)  = ta1;
    *(half8_t*)(arec + 16) = da0;  *(half8_t*)(arec + 24) = da1;
    *(half8_t*)(brec + 0)  = tb0;  *(half8_t*)(brec + 8)  = tb1;
    *(half8_t*)(brec + 16) = db0;  *(half8_t*)(brec + 24) = db1;
}

__device__ __forceinline__ half8_t ld8(const _Float16* p) {
    return *(const half8_t*)p;
}

__global__ __launch_bounds__(256, 4)
void pair_sum_kernel(const _Float16* __restrict__ fd,
                     float*          __restrict__ out) {
    const int b       = blockIdx.z;
    const int pairIdx = blockIdx.x / SPLITS;     // 0..38
    const int s       = blockIdx.x % SPLITS;

    const _Float16* Arec = fd;
    const _Float16* Brec = fd + (size_t)NTOT * 32;

    const int lane = threadIdx.x & 63;
    const int w    = threadIdx.x >> 6;
    const int col  = lane & 31;
    const int koff = (lane >> 5) * 8;

    const size_t bface = (size_t)b * NTP;
    const size_t JSTEP = (size_t)SPLITS * 32 * 32;

    float acc = 0.0f;

    #pragma unroll 1
    for (int h = 0; h < 2; ++h) {
        const int   P  = h ? (NPAN - 1 - pairIdx) : pairIdx;
        const int   c0 = 8 * P;
        const float si = (P < NPAN / 2) ? 1.0f : -1.0f;
        const int   iters = (NCH - c0 - s + SPLITS - 1) / SPLITS;
        if (iters <= 0) continue;

        // two i-tiles per wave: rows P*256 + w*32 (+128)
        const _Float16* ap0 = Arec + (bface + (size_t)(P * 256 + w * 32 + col)) * 32 + koff;
        const _Float16* ap1 = ap0 + (size_t)128 * 32;
        half8_t aT0 = ld8(ap0);
        half8_t aD0 = ld8(ap0 + 16);
        half8_t aT1 = ld8(ap1);
        half8_t aD1 = ld8(ap1 + 16);

        const _Float16* pB = Brec + (bface + (size_t)((c0 + s) * 32 + col)) * 32 + koff;
        half8_t bT = ld8(pB);
        half8_t bD = ld8(pB + 16);

        f32x16 z = {};

        #pragma unroll 1
        for (int k = 0; k < iters; ++k) {
            // depth-1 branchless prefetch of next chunk (clamped)
            const _Float16* pN = (k + 1 < iters) ? (pB + JSTEP) : pB;
            half8_t nT = ld8(pN);
            half8_t nD = ld8(pN + 16);
            pB = pN;

            // one B-chunk feeds both i-tiles: 4 MFMAs / 2048 pairs
            f32x16 T0 = __builtin_amdgcn_mfma_f32_32x32x16_f16(aT0, bT, z, 0, 0, 0);
            f32x16 D0 = __builtin_amdgcn_mfma_f32_32x32x16_f16(aD0, bD, z, 0, 0, 0);
            f32x16 T1 = __builtin_amdgcn_mfma_f32_32x32x16_f16(aT1, bT, z, 0, 0, 0);
            f32x16 D1 = __builtin_amdgcn_mfma_f32_32x32x16_f16(aD1, bD, z, 0, 0, 0);

            // two independent packed epilogues
            f32x2 ts0 = {0.f, 0.f}, ts1 = {0.f, 0.f};
            #pragma unroll
            for (int r = 0; r < 16; r += 2) {
                f32x2 e0 = {__builtin_amdgcn_exp2f(T0[r]),
                            __builtin_amdgcn_exp2f(T0[r + 1])};
                f32x2 d0 = {D0[r], D0[r + 1]};
                d0 = d0 * d0;
                ts0 = e0 * d0 + ts0;
                f32x2 e1 = {__builtin_amdgcn_exp2f(T1[r]),
                            __builtin_amdgcn_exp2f(T1[r + 1])};
                f32x2 d1 = {D1[r], D1[r + 1]};
                d1 = d1 * d1;
                ts1 = e1 * d1 + ts1;
            }

            const int   jc  = c0 + s + SPLITS * k;
            const float sj  = (jc < NCH / 2) ? si : -si;
            const float wgt = (k == 0 && s < 8) ? 1.0f : 2.0f;
            acc = fmaf(sj * wgt, ts0.x + ts0.y + ts1.x + ts1.y, acc);

            bT = nT; bD = nD;
        }
    }

    acc *= (1.0f / BATCH);

    #pragma unroll
    for (int off = 32; off > 0; off >>= 1)
        acc += __shfl_down(acc, off, 64);

    __shared__ float wsum[4];
    if (lane == 0) wsum[w] = acc;
    __syncthreads();
    if (threadIdx.x == 0)
        atomicAdd(out, wsum[0] + wsum[1] + wsum[2] + wsum[3]);
}

extern "C" void kernel_launch(void* const* d_in, const int* in_sizes, int n_in,
                              void* d_out, int out_size, void* d_ws, size_t ws_size,
                              hipStream_t stream) {
    const float* pred  = (const float*)d_in[0];
    const float* targ  = (const float*)d_in[1];
    const int*   faces = (const int*)d_in[2];
    float*       out   = (float*)d_out;
    _Float16*    fd    = (_Float16*)d_ws;   // 2 arrays x 79872 faces x 64 B = 10.2 MB

    face_quant_kernel<<<(NTOT + 255) / 256, 256, 0, stream>>>(
        pred, targ, faces, fd, out);

    dim3 grid((NPAN / 2) * SPLITS, 1, BATCH);   // 1014 x 1 x 4 = 4056 blocks
    pair_sum_kernel<<<grid, 256, 0, stream>>>(fd, out);
}